// Round 1
// baseline (410.517 us; speedup 1.0000x reference)
//
#include <hip/hip_runtime.h>
#include <hip/hip_fp16.h>

// ---------------------------------------------------------------------------
// HeteroIncidentGATv2: 3 bipartite GATv2 relations (H=4, C=32, HC=128)
//   hs: host->switch (200K), vh: vm->host (400K), jv: job->vm (800K)
//
// R13 changes vs R12 (389.6 us; mega 118 us @ 2.15 TB/s, MfmaUtil 2.7%,
// VALUBusy 9.9% == latency-bound, not BW-bound):
//   - mega GEMMs fused by node type: host and vm rows compute BOTH their
//     projections (lin_l of one relation + lin_r of another) from ONE
//     X load + fp16 A-fragment. 6 jobs -> 4 jobs, 7894 -> 5549 blocks,
//     -38 MB X re-fetch, -30% per-row load/convert work. Same MFMA FLOPs,
//     same writes. Second output tile reuses the per-wave LDS slice.
//   - everything else (init, link, agg3, alpha) unchanged from R12.
// ---------------------------------------------------------------------------

#define SLOPE_ATT 0.2f
#define SLOPE_OUT 0.01f

typedef _Float16 half8_t __attribute__((ext_vector_type(8)));
typedef _Float16 v2h_t __attribute__((ext_vector_type(2)));
typedef float float4_t __attribute__((ext_vector_type(4)));

__device__ __forceinline__ float dot8(half8_t a, half8_t b, float acc) {
    v2h_t a0 = __builtin_shufflevector(a, a, 0, 1);
    v2h_t a1 = __builtin_shufflevector(a, a, 2, 3);
    v2h_t a2 = __builtin_shufflevector(a, a, 4, 5);
    v2h_t a3 = __builtin_shufflevector(a, a, 6, 7);
    v2h_t b0 = __builtin_shufflevector(b, b, 0, 1);
    v2h_t b1 = __builtin_shufflevector(b, b, 2, 3);
    v2h_t b2 = __builtin_shufflevector(b, b, 4, 5);
    v2h_t b3 = __builtin_shufflevector(b, b, 6, 7);
    acc = __builtin_amdgcn_fdot2(a0, b0, acc, false);
    acc = __builtin_amdgcn_fdot2(a1, b1, acc, false);
    acc = __builtin_amdgcn_fdot2(a2, b2, acc, false);
    acc = __builtin_amdgcn_fdot2(a3, b3, acc, false);
    return acc;
}

// ---------------------------------------------------------------------------
// L0: head = -1  +  convert 6 W matrices to fp16 transposed [n][k] layout.
// ---------------------------------------------------------------------------
struct WSrc { const float* W[6]; };

__global__ __launch_bounds__(256) void init_wt_kernel(
    int* __restrict__ head, int ptot, WSrc wsrc, __half* __restrict__ Wt) {
    int i = blockIdx.x * 256 + threadIdx.x;
    if (i < ptot) {
        head[i] = -1;
    } else {
        int r = i - ptot;
        if (r < 6 * 8192) {
            int j = r >> 13;           // which W
            int rr = r & 8191;         // n*64 + k
            int n = rr >> 6, k = rr & 63;
            Wt[r] = (__half)wsrc.W[j][k * 128 + n];
        }
    }
}

// ---------------------------------------------------------------------------
// MFMA GEMM pass: given preloaded A-frags for a 16-row strip, compute
// Y[16,128](fp16) = A @ W(fp16,[n][k]) + b and store via LDS transpose.
// Frag layouts (gfx950 16x16x32): A[m=lane&15][k=quad*8+j],
// B[n=lane&15][k=quad*8+j], C/D col=lane&15, row=quad*4+reg.
// Each wave owns its own sY[wv] slice; __syncthreads orders write->read.
// ---------------------------------------------------------------------------
__device__ __forceinline__ void gemm_pass(
    half8_t a0, half8_t a1, const __half* __restrict__ Wt,
    const float* __restrict__ bb, __half* __restrict__ Y,
    int M, int m0, int lane, int wv, __half (*sY)[16][136]) {
    const int mr = lane & 15;
    const int quad = lane >> 4;

#pragma unroll
    for (int t = 0; t < 8; t++) {
        const __half* wb = Wt + ((size_t)(t * 16 + mr)) * 64 + quad * 8;
        half8_t b0 = *(const half8_t*)wb;
        half8_t b1 = *(const half8_t*)(wb + 32);
        float4_t c = {0.f, 0.f, 0.f, 0.f};
        c = __builtin_amdgcn_mfma_f32_16x16x32_f16(a0, b0, c, 0, 0, 0);
        c = __builtin_amdgcn_mfma_f32_16x16x32_f16(a1, b1, c, 0, 0, 0);
        int ocol = t * 16 + mr;
        float bv = bb[ocol];
        int lrow = quad * 4;
#pragma unroll
        for (int r = 0; r < 4; r++)
            sY[wv][lrow + r][ocol] = (__half)(c[r] + bv);
    }

    __syncthreads();

    const int rl = lane >> 4;
    const int c8 = (lane & 15) * 8;
#pragma unroll
    for (int i = 0; i < 4; i++) {
        int row = i * 4 + rl;
        int gr2 = m0 + row;
        if (gr2 < M) {
            half8_t v = *(const half8_t*)&sY[wv][row][c8];
            *(half8_t*)&Y[(size_t)gr2 * 128 + c8] = v;
        }
    }
}

// ---------------------------------------------------------------------------
// Linked-list build: old = atomicExch(&head[slot], le); nxt[ge] = {old, src}
// ---------------------------------------------------------------------------
__device__ __forceinline__ void link_work(
    int linkId, int linkBlocks,
    const int* __restrict__ d0, const int* __restrict__ s0,
    const int* __restrict__ d1, const int* __restrict__ s1,
    const int* __restrict__ d2, const int* __restrict__ s2,
    int* __restrict__ head, int2* __restrict__ nxt,
    int E0, int E1, int E2, int pb1, int pb2) {
    int i = linkId * 256 + threadIdx.x;
    int Etot = E0 + E1 + E2;
    int stride = linkBlocks * 256;
    for (; i < Etot; i += stride) {
        int le, slot; const int* sp;
        if (i < E0)           { le = i;           slot = d0[le];       sp = s0; }
        else if (i < E0 + E1) { le = i - E0;      slot = pb1 + d1[le]; sp = s1; }
        else                  { le = i - E0 - E1; slot = pb2 + d2[le]; sp = s2; }
        int old = atomicExch(&head[slot], le);
        nxt[i] = make_int2(old, sp[le]);
    }
}

// ---------------------------------------------------------------------------
// Mega: 4 node-type MFMA GEMM jobs (host/vm emit TWO projections from one
// A-frag load) + link3 (sparse, every s-th block).
// ---------------------------------------------------------------------------
struct GemmJobs {
    const float* X[4];
    const __half* W1[4]; const __half* W2[4];   // W2 == nullptr -> single
    const float* b1[4]; const float* b2[4];
    __half* Y1[4]; __half* Y2[4];
    int M[4]; int base[5];
};

__global__ __launch_bounds__(256) void mega_gemm_link_kernel(
    GemmJobs j, int s, int L,
    const int* __restrict__ d0, const int* __restrict__ s0,
    const int* __restrict__ d1, const int* __restrict__ s1,
    const int* __restrict__ d2, const int* __restrict__ s2,
    int* __restrict__ head, int2* __restrict__ nxt,
    int E0, int E1, int E2, int pb1, int pb2) {
    __shared__ __half sY[4][16][136];
    int b = blockIdx.x;
    int q = b / s;
    bool onGridline = (b - q * s) == 0;
    if (onGridline && q < L) {
        link_work(q, L, d0, s0, d1, s1, d2, s2, head, nxt, E0, E1, E2, pb1, pb2);
    } else {
        int before = q + (onGridline ? 0 : 1);
        if (before > L) before = L;
        int g = b - before;
        int k = 0;
        while (g >= j.base[k + 1]) k++;

        const int lane = threadIdx.x & 63;
        const int wv = threadIdx.x >> 6;
        const int m0 = (g - j.base[k]) * 64 + wv * 16;
        const int mr = lane & 15;
        const int quad = lane >> 4;
        const int gr = m0 + mr;
        const int M = j.M[k];

        // load A-fragments once (fp32 -> fp16), reused for both projections
        half8_t a0 = {}, a1 = {};
        if (gr < M) {
            const float* X = j.X[k];
            const float4* xp = (const float4*)(X + (size_t)gr * 64 + quad * 8);
            float4 xa = xp[0], xb = xp[1];
            const float4* xq = (const float4*)(X + (size_t)gr * 64 + 32 + quad * 8);
            float4 xc = xq[0], xd = xq[1];
            a0[0] = (_Float16)xa.x; a0[1] = (_Float16)xa.y;
            a0[2] = (_Float16)xa.z; a0[3] = (_Float16)xa.w;
            a0[4] = (_Float16)xb.x; a0[5] = (_Float16)xb.y;
            a0[6] = (_Float16)xb.z; a0[7] = (_Float16)xb.w;
            a1[0] = (_Float16)xc.x; a1[1] = (_Float16)xc.y;
            a1[2] = (_Float16)xc.z; a1[3] = (_Float16)xc.w;
            a1[4] = (_Float16)xd.x; a1[5] = (_Float16)xd.y;
            a1[6] = (_Float16)xd.z; a1[7] = (_Float16)xd.w;
        }

        gemm_pass(a0, a1, j.W1[k], j.b1[k], j.Y1[k], M, m0, lane, wv, sY);
        if (j.W2[k]) {
            __syncthreads();   // pass-1 LDS reads done before pass-2 writes
            gemm_pass(a0, a1, j.W2[k], j.b2[k], j.Y2[k], M, m0, lane, wv, sY);
        }
    }
}

// ---------------------------------------------------------------------------
// Fused GATv2 aggregate: 8 dst per 64-lane wave (8 lanes/dst, 16 ch/lane).
// Per group: walk the dst's chain; per edge: in-lane fdot2 over 16 ch +
// one shfl_xor(1) -> head logit; w = exp(p); acc += w*x (fp32, 16 ch).
// ex/dn writes 16B-contiguous per group. Fused readout epilogue.
// ---------------------------------------------------------------------------
struct AggJob {
    const __half* xl; const __half* xr; const float* att;
    const int* head; const int2* nxt;
    float* ex; float* dn;
    const float* bias; const float* Wn; const float* bn; float* scores;
    int Nd;
};
struct AggJobs { AggJob r[3]; int base[4]; };   // base in BLOCKS (32 dst/block)

__global__ __launch_bounds__(256) void agg3_kernel(AggJobs aj) {
    int b = blockIdx.x;
    int k = 0;
    while (b >= aj.base[k + 1]) k++;
    AggJob J = aj.r[k];

    const int l = threadIdx.x & 63;
    const int wv = threadIdx.x >> 6;
    const int li = l & 7;                 // lane in group
    const int g = l >> 3;                 // group 0..7
    const int dbase = ((b - aj.base[k]) * 4 + wv) * 8;
    const int d = dbase + g;
    if (dbase >= J.Nd) return;
    const bool dok = d < J.Nd;
    const int h = li >> 1;                // my head (pair of lanes per head)

    // my 16 channels: 2 x half8
    half8_t xr0 = {}, xr1 = {};
    if (dok) {
        const half8_t* xrp = (const half8_t*)(J.xr + (size_t)d * 128) + li * 2;
        xr0 = xrp[0]; xr1 = xrp[1];
    }
    half8_t at0, at1;
    {
        const float* ap = J.att + li * 16;
#pragma unroll
        for (int i = 0; i < 8; i++) {
            at0[i] = (_Float16)ap[i];
            at1[i] = (_Float16)ap[8 + i];
        }
    }
    const half8_t sl8 = {(_Float16)SLOPE_ATT, (_Float16)SLOPE_ATT,
                         (_Float16)SLOPE_ATT, (_Float16)SLOPE_ATT,
                         (_Float16)SLOPE_ATT, (_Float16)SLOPE_ATT,
                         (_Float16)SLOPE_ATT, (_Float16)SLOPE_ATT};

    float acc[16] = {};
    float ssum = 0.f;

    int e = dok ? J.head[d] : -1;
    const bool any = (e >= 0);

    while (__any(e >= 0)) {
        bool act = (e >= 0);
        int2 ns = act ? J.nxt[e] : make_int2(-1, 0);
        half8_t x0 = {}, x1 = {};
        if (act) {
            const half8_t* xp = (const half8_t*)(J.xl + (size_t)ns.y * 128) + li * 2;
            x0 = xp[0]; x1 = xp[1];
        }
        if (act) {
            half8_t v0 = x0 + xr0;
            half8_t v1 = x1 + xr1;
            half8_t lk0 = __builtin_elementwise_max(v0, v0 * sl8);
            half8_t lk1 = __builtin_elementwise_max(v1, v1 * sl8);
            float p = dot8(lk1, at1, dot8(lk0, at0, 0.f));
            p += __shfl_xor(p, 1);            // pair shares one head
            float w = __expf(p);
            if ((li & 1) == 0) J.ex[(size_t)e * 4 + h] = w;
            ssum += w;
#pragma unroll
            for (int i = 0; i < 8; i++) {
                acc[i]     += w * (float)x0[i];
                acc[8 + i] += w * (float)x1[i];
            }
        }
        e = act ? ns.x : -1;
    }

    if (dok && (li & 1) == 0) J.dn[(size_t)d * 4 + h] = ssum;

    // readout: sigmoid(lrelu(acc/ssum + bias, .01) . Wn + bn)
    float rr = any ? 1.f / ssum : 0.f;
    float pr = 0.f;
    if (dok) {
        const float* bp = J.bias + li * 16;
        const float* wp = J.Wn + li * 16;
#pragma unroll
        for (int i = 0; i < 16; i++) {
            float o = acc[i] * rr + bp[i];
            o = o > 0.f ? o : SLOPE_OUT * o;
            pr += o * wp[i];
        }
    }
    pr += __shfl_xor(pr, 1);
    pr += __shfl_xor(pr, 2);
    pr += __shfl_xor(pr, 4);
    if (dok && li == 0)
        J.scores[d] = 1.f / (1.f + __expf(-(pr + J.bn[0])));
}

// ---------------------------------------------------------------------------
// Merged: alpha (= ex/dn) for all relations + job scores.
// ---------------------------------------------------------------------------
__global__ __launch_bounds__(256) void alpha_job_kernel(
    float* __restrict__ ex,
    const int* __restrict__ d0, const int* __restrict__ d1,
    const int* __restrict__ d2,
    const float* __restrict__ dn,
    int E0, int E1, int E2, int pb1, int pb2, int ab,
    const float* __restrict__ bjob, float* __restrict__ sjob, int NJ) {
    int b = blockIdx.x;
    if (b < ab) {
        int i = b * 256 + threadIdx.x;
        int tot = (E0 + E1 + E2) * 4;
        if (i >= tot) return;
        int e = i >> 2, h = i & 3;
        int d;
        if (e < E0)           d = d0[e];
        else if (e < E0 + E1) d = pb1 + d1[e - E0];
        else                  d = pb2 + d2[e - E0 - E1];
        ex[i] = ex[i] / dn[(size_t)d * 4 + h];
    } else {
        int i = (b - ab) * 256 + threadIdx.x;
        if (i < NJ) sjob[i] = 1.f / (1.f + __expf(-bjob[0]));
    }
}

// ---------------------------------------------------------------------------

extern "C" void kernel_launch(void* const* d_in, const int* in_sizes, int n_in,
                              void* d_out, int out_size, void* d_ws, size_t ws_size,
                              hipStream_t stream) {
    const float* x_host   = (const float*)d_in[0];
    const float* x_vm     = (const float*)d_in[1];
    const float* x_job    = (const float*)d_in[2];
    const float* x_switch = (const float*)d_in[3];
    const int* e_hs_src = (const int*)d_in[4];
    const int* e_hs_dst = (const int*)d_in[5];
    const int* e_vh_src = (const int*)d_in[6];
    const int* e_vh_dst = (const int*)d_in[7];
    const int* e_jv_src = (const int*)d_in[8];
    const int* e_jv_dst = (const int*)d_in[9];
    const float* Wl_hs = (const float*)d_in[10];
    const float* bl_hs = (const float*)d_in[11];
    const float* Wr_hs = (const float*)d_in[12];
    const float* br_hs = (const float*)d_in[13];
    const float* att_hs = (const float*)d_in[14];
    const float* bias_hs = (const float*)d_in[15];
    const float* Wl_vh = (const float*)d_in[16];
    const float* bl_vh = (const float*)d_in[17];
    const float* Wr_vh = (const float*)d_in[18];
    const float* br_vh = (const float*)d_in[19];
    const float* att_vh = (const float*)d_in[20];
    const float* bias_vh = (const float*)d_in[21];
    const float* Wl_jv = (const float*)d_in[22];
    const float* bl_jv = (const float*)d_in[23];
    const float* Wr_jv = (const float*)d_in[24];
    const float* br_jv = (const float*)d_in[25];
    const float* att_jv = (const float*)d_in[26];
    const float* bias_jv = (const float*)d_in[27];
    const float* W_host   = (const float*)d_in[28];
    const float* b_host   = (const float*)d_in[29];
    const float* W_vm     = (const float*)d_in[30];
    const float* b_vm     = (const float*)d_in[31];
    const float* W_job    = (const float*)d_in[32];
    const float* b_job    = (const float*)d_in[33];
    const float* W_switch = (const float*)d_in[34];
    const float* b_switch = (const float*)d_in[35];

    const int NH  = in_sizes[0] / 64;
    const int NV  = in_sizes[1] / 64;
    const int NJ  = in_sizes[2] / 64;
    const int NSW = in_sizes[3] / 64;
    const int EHS = in_sizes[4];
    const int EVH = in_sizes[6];
    const int EJV = in_sizes[8];
    const int Etot = EHS + EVH + EJV;

    float* out = (float*)d_out;
    float* s_host = out;
    float* s_vm = out + NH;
    float* s_job = out + NH + NV;
    float* s_sw = out + NH + NV + NJ;
    float* a_hs = out + NH + NV + NJ + NSW;
    float* a_vh = a_hs + (size_t)EHS * 4;
    float* a_jv = a_vh + (size_t)EVH * 4;

    const int pb1 = ((NSW + 255) / 256) * 256;
    const int pb2 = pb1 + ((NH + 255) / 256) * 256;
    const int ptot = pb2 + ((NV + 255) / 256) * 256;

    // -------- ws layout (~137 MB total) --------
    float* ws = (float*)d_ws;
    int2* nxt_all = (int2*)ws;                              // Etot int2
    int* head_all = (int*)(nxt_all + Etot);                 // ptot
    float* dn_all = (float*)(head_all + ptot);              // ptot*4
    __half* Wt    = (__half*)(dn_all + (size_t)ptot * 4);   // 6*8192 fp16
    __half* mats  = Wt + 6 * 8192;
    __half* xl_hs = mats;                                   // NH*128
    __half* xr_hs = xl_hs + (size_t)NH * 128;               // NSW*128
    __half* xl_vh = xr_hs + (size_t)NSW * 128;              // NV*128
    __half* xr_vh = xl_vh + (size_t)NV * 128;               // NH*128
    __half* xl_jv = xr_vh + (size_t)NH * 128;               // NJ*128
    __half* xr_jv = xl_jv + (size_t)NJ * 128;               // NV*128

    // L0: head = -1 + Wt conversion
    {
        WSrc w;
        w.W[0] = Wl_hs; w.W[1] = Wr_hs; w.W[2] = Wl_vh;
        w.W[3] = Wr_vh; w.W[4] = Wl_jv; w.W[5] = Wr_jv;
        int tot = ptot + 6 * 8192;
        init_wt_kernel<<<(tot + 255) / 256, 256, 0, stream>>>(head_all, ptot, w, Wt);
    }

    // L1: mega = 4 fused node-type MFMA GEMMs + link3
    {
        GemmJobs j;
        // job order: host (xl_hs + xr_vh), vm (xl_vh + xr_jv), job (xl_jv), switch (xr_hs)
        const float* Xs[4]  = {x_host, x_vm, x_job, x_switch};
        int w1i[4]          = {0, 2, 4, 1};     // Wl_hs, Wl_vh, Wl_jv, Wr_hs
        int w2i[4]          = {3, 5, -1, -1};   // Wr_vh, Wr_jv, -, -
        const float* b1s[4] = {bl_hs, bl_vh, bl_jv, br_hs};
        const float* b2s[4] = {br_vh, br_jv, nullptr, nullptr};
        __half* Y1s[4]      = {xl_hs, xl_vh, xl_jv, xr_hs};
        __half* Y2s[4]      = {xr_vh, xr_jv, nullptr, nullptr};
        int Ms[4]           = {NH, NV, NJ, NSW};
        int base = 0;
        for (int k = 0; k < 4; k++) {
            j.X[k] = Xs[k];
            j.W1[k] = Wt + (size_t)w1i[k] * 8192;
            j.W2[k] = (w2i[k] >= 0) ? (Wt + (size_t)w2i[k] * 8192) : nullptr;
            j.b1[k] = b1s[k]; j.b2[k] = b2s[k];
            j.Y1[k] = Y1s[k]; j.Y2[k] = Y2s[k];
            j.M[k] = Ms[k];
            j.base[k] = base;
            base += (Ms[k] + 63) / 64;
        }
        j.base[4] = base;
        int L = 3072;
        int T = base + L;
        int s = T / L; if (s < 1) s = 1;
        mega_gemm_link_kernel<<<T, 256, 0, stream>>>(
            j, s, L, e_hs_dst, e_hs_src, e_vh_dst, e_vh_src,
            e_jv_dst, e_jv_src, head_all, nxt_all, EHS, EVH, EJV, pb1, pb2);
    }

    // L2: merged agg (3 relations, 32 dst per block)
    {
        AggJobs aj;
        aj.r[0] = {xl_hs, xr_hs, att_hs, head_all + 0, nxt_all + 0,
                   a_hs, dn_all + 0,
                   bias_hs, W_switch, b_switch, s_sw, NSW};
        aj.r[1] = {xl_vh, xr_vh, att_vh, head_all + pb1, nxt_all + EHS,
                   a_vh, dn_all + (size_t)pb1 * 4,
                   bias_vh, W_host, b_host, s_host, NH};
        aj.r[2] = {xl_jv, xr_jv, att_jv, head_all + pb2, nxt_all + (EHS + EVH),
                   a_jv, dn_all + (size_t)pb2 * 4,
                   bias_jv, W_vm, b_vm, s_vm, NV};
        aj.base[0] = 0;
        aj.base[1] = (NSW + 31) / 32;
        aj.base[2] = aj.base[1] + (NH + 31) / 32;
        aj.base[3] = aj.base[2] + (NV + 31) / 32;
        agg3_kernel<<<aj.base[3], 256, 0, stream>>>(aj);
    }

    // L3: alpha (all relations) + job scores
    {
        int ab = (Etot * 4 + 255) / 256;
        int jb = (NJ + 255) / 256;
        alpha_job_kernel<<<ab + jb, 256, 0, stream>>>(
            a_hs, e_hs_dst, e_vh_dst, e_jv_dst, dn_all,
            EHS, EVH, EJV, pb1, pb2, ab, b_job, s_job, NJ);
    }
}

// Round 2
// 392.254 us; speedup vs baseline: 1.0466x; 1.0466x over previous
//
#include <hip/hip_runtime.h>
#include <hip/hip_fp16.h>

// ---------------------------------------------------------------------------
// HeteroIncidentGATv2: 3 bipartite GATv2 relations (H=4, C=32, HC=128)
//   hs: host->switch (200K), vh: vm->host (400K), jv: job->vm (800K)
//
// R14 changes vs R13 (410us, REGRESSION - reverted) / R12 (389.6us):
//   - structure reverted to R12: 6 independent GEMM jobs (max block count,
//     min per-block critical path; R13 proved latency-bound regime).
//   - gemm_tile_mfma: ALL 16 W-fragment loads + 8 bias loads hoisted ahead
//     of the MFMA loop (one wave exposes one load-latency, not nine;
//     ~28 loads in flight per wave vs ~2). VGPR ~40 -> ~110 is a deliberate
//     occupancy-for-MLP trade (counters: waves were parked, VALUBusy 10%).
//   - __syncthreads removed from the GEMM tile: each wave only touches its
//     own sY[wv] slice; same-wave DS ops are in-order, so the barrier only
//     coupled waves to the slowest sibling's X-load drain.
//   - everything else (init, link, agg3, alpha) unchanged from R12.
// ---------------------------------------------------------------------------

#define SLOPE_ATT 0.2f
#define SLOPE_OUT 0.01f

typedef _Float16 half8_t __attribute__((ext_vector_type(8)));
typedef _Float16 v2h_t __attribute__((ext_vector_type(2)));
typedef float float4_t __attribute__((ext_vector_type(4)));

__device__ __forceinline__ float dot8(half8_t a, half8_t b, float acc) {
    v2h_t a0 = __builtin_shufflevector(a, a, 0, 1);
    v2h_t a1 = __builtin_shufflevector(a, a, 2, 3);
    v2h_t a2 = __builtin_shufflevector(a, a, 4, 5);
    v2h_t a3 = __builtin_shufflevector(a, a, 6, 7);
    v2h_t b0 = __builtin_shufflevector(b, b, 0, 1);
    v2h_t b1 = __builtin_shufflevector(b, b, 2, 3);
    v2h_t b2 = __builtin_shufflevector(b, b, 4, 5);
    v2h_t b3 = __builtin_shufflevector(b, b, 6, 7);
    acc = __builtin_amdgcn_fdot2(a0, b0, acc, false);
    acc = __builtin_amdgcn_fdot2(a1, b1, acc, false);
    acc = __builtin_amdgcn_fdot2(a2, b2, acc, false);
    acc = __builtin_amdgcn_fdot2(a3, b3, acc, false);
    return acc;
}

// ---------------------------------------------------------------------------
// L0: head = -1  +  convert 6 W matrices to fp16 transposed [n][k] layout.
// ---------------------------------------------------------------------------
struct WSrc { const float* W[6]; };

__global__ __launch_bounds__(256) void init_wt_kernel(
    int* __restrict__ head, int ptot, WSrc wsrc, __half* __restrict__ Wt) {
    int i = blockIdx.x * 256 + threadIdx.x;
    if (i < ptot) {
        head[i] = -1;
    } else {
        int r = i - ptot;
        if (r < 6 * 8192) {
            int j = r >> 13;           // which W
            int rr = r & 8191;         // n*64 + k
            int n = rr >> 6, k = rr & 63;
            Wt[r] = (__half)wsrc.W[j][k * 128 + n];
        }
    }
}

// ---------------------------------------------------------------------------
// MFMA GEMM tile: Y[64,128](fp16) = X[64,64](fp32) @ W(fp16,[n][k]) + b
// Frag layouts (gfx950 16x16x32): A[m=lane&15][k=quad*8+j],
// B[n=lane&15][k=quad*8+j], C/D col=lane&15, row=quad*4+reg.
// All W/bias loads hoisted (MLP); no barrier: per-wave sY slice, same-wave
// DS ops are in-order so the LDS transpose needs no cross-wave sync.
// ---------------------------------------------------------------------------
__device__ __forceinline__ void gemm_tile_mfma(
    const float* __restrict__ X, const __half* __restrict__ Wt,
    const float* __restrict__ bb, __half* __restrict__ Y,
    int M, int block_row, __half (*sY)[16][136]) {
    const int lane = threadIdx.x & 63;
    const int wv = threadIdx.x >> 6;
    const int m0 = block_row + wv * 16;
    const int mr = lane & 15;
    const int quad = lane >> 4;
    const int gr = m0 + mr;
    const bool valid = gr < M;

    // X fragments first (HBM, longest latency)
    half8_t a0 = {}, a1 = {};
    float4 xa = {}, xb = {}, xc = {}, xd = {};
    if (valid) {
        const float4* xp = (const float4*)(X + (size_t)gr * 64 + quad * 8);
        xa = xp[0]; xb = xp[1];
        const float4* xq = (const float4*)(X + (size_t)gr * 64 + 32 + quad * 8);
        xc = xq[0]; xd = xq[1];
    }

    // hoist ALL 16 W-fragment loads (L2-hot) + 8 bias loads -> max MLP
    half8_t wb0[8], wb1[8];
    float bv[8];
#pragma unroll
    for (int t = 0; t < 8; t++) {
        const __half* wb = Wt + ((size_t)(t * 16 + mr)) * 64 + quad * 8;
        wb0[t] = *(const half8_t*)wb;
        wb1[t] = *(const half8_t*)(wb + 32);
        bv[t] = bb[t * 16 + mr];
    }

    a0[0] = (_Float16)xa.x; a0[1] = (_Float16)xa.y;
    a0[2] = (_Float16)xa.z; a0[3] = (_Float16)xa.w;
    a0[4] = (_Float16)xb.x; a0[5] = (_Float16)xb.y;
    a0[6] = (_Float16)xb.z; a0[7] = (_Float16)xb.w;
    a1[0] = (_Float16)xc.x; a1[1] = (_Float16)xc.y;
    a1[2] = (_Float16)xc.z; a1[3] = (_Float16)xc.w;
    a1[4] = (_Float16)xd.x; a1[5] = (_Float16)xd.y;
    a1[6] = (_Float16)xd.z; a1[7] = (_Float16)xd.w;

#pragma unroll
    for (int t = 0; t < 8; t++) {
        float4_t c = {0.f, 0.f, 0.f, 0.f};
        c = __builtin_amdgcn_mfma_f32_16x16x32_f16(a0, wb0[t], c, 0, 0, 0);
        c = __builtin_amdgcn_mfma_f32_16x16x32_f16(a1, wb1[t], c, 0, 0, 0);
        int ocol = t * 16 + mr;
        int lrow = quad * 4;
#pragma unroll
        for (int r = 0; r < 4; r++)
            sY[wv][lrow + r][ocol] = (__half)(c[r] + bv[t]);
    }

    // no __syncthreads(): sY[wv] is private to this wave; DS pipe is in-order
    const int rl = lane >> 4;
    const int c8 = (lane & 15) * 8;
#pragma unroll
    for (int i = 0; i < 4; i++) {
        int row = i * 4 + rl;
        int gr2 = m0 + row;
        if (gr2 < M) {
            half8_t v = *(const half8_t*)&sY[wv][row][c8];
            *(half8_t*)&Y[(size_t)gr2 * 128 + c8] = v;
        }
    }
}

// ---------------------------------------------------------------------------
// Linked-list build: old = atomicExch(&head[slot], le); nxt[ge] = {old, src}
// ---------------------------------------------------------------------------
__device__ __forceinline__ void link_work(
    int linkId, int linkBlocks,
    const int* __restrict__ d0, const int* __restrict__ s0,
    const int* __restrict__ d1, const int* __restrict__ s1,
    const int* __restrict__ d2, const int* __restrict__ s2,
    int* __restrict__ head, int2* __restrict__ nxt,
    int E0, int E1, int E2, int pb1, int pb2) {
    int i = linkId * 256 + threadIdx.x;
    int Etot = E0 + E1 + E2;
    int stride = linkBlocks * 256;
    for (; i < Etot; i += stride) {
        int le, slot; const int* sp;
        if (i < E0)           { le = i;           slot = d0[le];       sp = s0; }
        else if (i < E0 + E1) { le = i - E0;      slot = pb1 + d1[le]; sp = s1; }
        else                  { le = i - E0 - E1; slot = pb2 + d2[le]; sp = s2; }
        int old = atomicExch(&head[slot], le);
        nxt[i] = make_int2(old, sp[le]);
    }
}

// ---------------------------------------------------------------------------
// Mega: 6 MFMA GEMM jobs (dense) + link3 (sparse, every s-th block).
// ---------------------------------------------------------------------------
struct GemmJobs {
    const float* X[6]; const float* b[6]; __half* Y[6];
    int M[6]; int base[7];
};

__global__ __launch_bounds__(256) void mega_gemm_link_kernel(
    GemmJobs j, const __half* __restrict__ Wt, int s, int L,
    const int* __restrict__ d0, const int* __restrict__ s0,
    const int* __restrict__ d1, const int* __restrict__ s1,
    const int* __restrict__ d2, const int* __restrict__ s2,
    int* __restrict__ head, int2* __restrict__ nxt,
    int E0, int E1, int E2, int pb1, int pb2) {
    __shared__ __half sY[4][16][136];
    int b = blockIdx.x;
    int q = b / s;
    bool onGridline = (b - q * s) == 0;
    if (onGridline && q < L) {
        link_work(q, L, d0, s0, d1, s1, d2, s2, head, nxt, E0, E1, E2, pb1, pb2);
    } else {
        int before = q + (onGridline ? 0 : 1);
        if (before > L) before = L;
        int g = b - before;
        int k = 0;
        while (g >= j.base[k + 1]) k++;
        gemm_tile_mfma(j.X[k], Wt + (size_t)k * 8192, j.b[k], j.Y[k], j.M[k],
                       (g - j.base[k]) * 64, sY);
    }
}

// ---------------------------------------------------------------------------
// Fused GATv2 aggregate: 8 dst per 64-lane wave (8 lanes/dst, 16 ch/lane).
// Per group: walk the dst's chain; per edge: in-lane fdot2 over 16 ch +
// one shfl_xor(1) -> head logit; w = exp(p); acc += w*x (fp32, 16 ch).
// ex/dn writes 16B-contiguous per group. Fused readout epilogue.
// ---------------------------------------------------------------------------
struct AggJob {
    const __half* xl; const __half* xr; const float* att;
    const int* head; const int2* nxt;
    float* ex; float* dn;
    const float* bias; const float* Wn; const float* bn; float* scores;
    int Nd;
};
struct AggJobs { AggJob r[3]; int base[4]; };   // base in BLOCKS (32 dst/block)

__global__ __launch_bounds__(256) void agg3_kernel(AggJobs aj) {
    int b = blockIdx.x;
    int k = 0;
    while (b >= aj.base[k + 1]) k++;
    AggJob J = aj.r[k];

    const int l = threadIdx.x & 63;
    const int wv = threadIdx.x >> 6;
    const int li = l & 7;                 // lane in group
    const int g = l >> 3;                 // group 0..7
    const int dbase = ((b - aj.base[k]) * 4 + wv) * 8;
    const int d = dbase + g;
    if (dbase >= J.Nd) return;
    const bool dok = d < J.Nd;
    const int h = li >> 1;                // my head (pair of lanes per head)

    // my 16 channels: 2 x half8
    half8_t xr0 = {}, xr1 = {};
    if (dok) {
        const half8_t* xrp = (const half8_t*)(J.xr + (size_t)d * 128) + li * 2;
        xr0 = xrp[0]; xr1 = xrp[1];
    }
    half8_t at0, at1;
    {
        const float* ap = J.att + li * 16;
#pragma unroll
        for (int i = 0; i < 8; i++) {
            at0[i] = (_Float16)ap[i];
            at1[i] = (_Float16)ap[8 + i];
        }
    }
    const half8_t sl8 = {(_Float16)SLOPE_ATT, (_Float16)SLOPE_ATT,
                         (_Float16)SLOPE_ATT, (_Float16)SLOPE_ATT,
                         (_Float16)SLOPE_ATT, (_Float16)SLOPE_ATT,
                         (_Float16)SLOPE_ATT, (_Float16)SLOPE_ATT};

    float acc[16] = {};
    float ssum = 0.f;

    int e = dok ? J.head[d] : -1;
    const bool any = (e >= 0);

    while (__any(e >= 0)) {
        bool act = (e >= 0);
        int2 ns = act ? J.nxt[e] : make_int2(-1, 0);
        half8_t x0 = {}, x1 = {};
        if (act) {
            const half8_t* xp = (const half8_t*)(J.xl + (size_t)ns.y * 128) + li * 2;
            x0 = xp[0]; x1 = xp[1];
        }
        if (act) {
            half8_t v0 = x0 + xr0;
            half8_t v1 = x1 + xr1;
            half8_t lk0 = __builtin_elementwise_max(v0, v0 * sl8);
            half8_t lk1 = __builtin_elementwise_max(v1, v1 * sl8);
            float p = dot8(lk1, at1, dot8(lk0, at0, 0.f));
            p += __shfl_xor(p, 1);            // pair shares one head
            float w = __expf(p);
            if ((li & 1) == 0) J.ex[(size_t)e * 4 + h] = w;
            ssum += w;
#pragma unroll
            for (int i = 0; i < 8; i++) {
                acc[i]     += w * (float)x0[i];
                acc[8 + i] += w * (float)x1[i];
            }
        }
        e = act ? ns.x : -1;
    }

    if (dok && (li & 1) == 0) J.dn[(size_t)d * 4 + h] = ssum;

    // readout: sigmoid(lrelu(acc/ssum + bias, .01) . Wn + bn)
    float rr = any ? 1.f / ssum : 0.f;
    float pr = 0.f;
    if (dok) {
        const float* bp = J.bias + li * 16;
        const float* wp = J.Wn + li * 16;
#pragma unroll
        for (int i = 0; i < 16; i++) {
            float o = acc[i] * rr + bp[i];
            o = o > 0.f ? o : SLOPE_OUT * o;
            pr += o * wp[i];
        }
    }
    pr += __shfl_xor(pr, 1);
    pr += __shfl_xor(pr, 2);
    pr += __shfl_xor(pr, 4);
    if (dok && li == 0)
        J.scores[d] = 1.f / (1.f + __expf(-(pr + J.bn[0])));
}

// ---------------------------------------------------------------------------
// Merged: alpha (= ex/dn) for all relations + job scores.
// ---------------------------------------------------------------------------
__global__ __launch_bounds__(256) void alpha_job_kernel(
    float* __restrict__ ex,
    const int* __restrict__ d0, const int* __restrict__ d1,
    const int* __restrict__ d2,
    const float* __restrict__ dn,
    int E0, int E1, int E2, int pb1, int pb2, int ab,
    const float* __restrict__ bjob, float* __restrict__ sjob, int NJ) {
    int b = blockIdx.x;
    if (b < ab) {
        int i = b * 256 + threadIdx.x;
        int tot = (E0 + E1 + E2) * 4;
        if (i >= tot) return;
        int e = i >> 2, h = i & 3;
        int d;
        if (e < E0)           d = d0[e];
        else if (e < E0 + E1) d = pb1 + d1[e - E0];
        else                  d = pb2 + d2[e - E0 - E1];
        ex[i] = ex[i] / dn[(size_t)d * 4 + h];
    } else {
        int i = (b - ab) * 256 + threadIdx.x;
        if (i < NJ) sjob[i] = 1.f / (1.f + __expf(-bjob[0]));
    }
}

// ---------------------------------------------------------------------------

extern "C" void kernel_launch(void* const* d_in, const int* in_sizes, int n_in,
                              void* d_out, int out_size, void* d_ws, size_t ws_size,
                              hipStream_t stream) {
    const float* x_host   = (const float*)d_in[0];
    const float* x_vm     = (const float*)d_in[1];
    const float* x_job    = (const float*)d_in[2];
    const float* x_switch = (const float*)d_in[3];
    const int* e_hs_src = (const int*)d_in[4];
    const int* e_hs_dst = (const int*)d_in[5];
    const int* e_vh_src = (const int*)d_in[6];
    const int* e_vh_dst = (const int*)d_in[7];
    const int* e_jv_src = (const int*)d_in[8];
    const int* e_jv_dst = (const int*)d_in[9];
    const float* Wl_hs = (const float*)d_in[10];
    const float* bl_hs = (const float*)d_in[11];
    const float* Wr_hs = (const float*)d_in[12];
    const float* br_hs = (const float*)d_in[13];
    const float* att_hs = (const float*)d_in[14];
    const float* bias_hs = (const float*)d_in[15];
    const float* Wl_vh = (const float*)d_in[16];
    const float* bl_vh = (const float*)d_in[17];
    const float* Wr_vh = (const float*)d_in[18];
    const float* br_vh = (const float*)d_in[19];
    const float* att_vh = (const float*)d_in[20];
    const float* bias_vh = (const float*)d_in[21];
    const float* Wl_jv = (const float*)d_in[22];
    const float* bl_jv = (const float*)d_in[23];
    const float* Wr_jv = (const float*)d_in[24];
    const float* br_jv = (const float*)d_in[25];
    const float* att_jv = (const float*)d_in[26];
    const float* bias_jv = (const float*)d_in[27];
    const float* W_host   = (const float*)d_in[28];
    const float* b_host   = (const float*)d_in[29];
    const float* W_vm     = (const float*)d_in[30];
    const float* b_vm     = (const float*)d_in[31];
    const float* W_job    = (const float*)d_in[32];
    const float* b_job    = (const float*)d_in[33];
    const float* W_switch = (const float*)d_in[34];
    const float* b_switch = (const float*)d_in[35];

    const int NH  = in_sizes[0] / 64;
    const int NV  = in_sizes[1] / 64;
    const int NJ  = in_sizes[2] / 64;
    const int NSW = in_sizes[3] / 64;
    const int EHS = in_sizes[4];
    const int EVH = in_sizes[6];
    const int EJV = in_sizes[8];
    const int Etot = EHS + EVH + EJV;

    float* out = (float*)d_out;
    float* s_host = out;
    float* s_vm = out + NH;
    float* s_job = out + NH + NV;
    float* s_sw = out + NH + NV + NJ;
    float* a_hs = out + NH + NV + NJ + NSW;
    float* a_vh = a_hs + (size_t)EHS * 4;
    float* a_jv = a_vh + (size_t)EVH * 4;

    const int pb1 = ((NSW + 255) / 256) * 256;
    const int pb2 = pb1 + ((NH + 255) / 256) * 256;
    const int ptot = pb2 + ((NV + 255) / 256) * 256;

    // -------- ws layout (~137 MB total) --------
    float* ws = (float*)d_ws;
    int2* nxt_all = (int2*)ws;                              // Etot int2
    int* head_all = (int*)(nxt_all + Etot);                 // ptot
    float* dn_all = (float*)(head_all + ptot);              // ptot*4
    __half* Wt    = (__half*)(dn_all + (size_t)ptot * 4);   // 6*8192 fp16
    __half* mats  = Wt + 6 * 8192;
    __half* xl_hs = mats;                                   // NH*128
    __half* xr_hs = xl_hs + (size_t)NH * 128;               // NSW*128
    __half* xl_vh = xr_hs + (size_t)NSW * 128;              // NV*128
    __half* xr_vh = xl_vh + (size_t)NV * 128;               // NH*128
    __half* xl_jv = xr_vh + (size_t)NH * 128;               // NJ*128
    __half* xr_jv = xl_jv + (size_t)NJ * 128;               // NV*128

    // L0: head = -1 + Wt conversion
    {
        WSrc w;
        w.W[0] = Wl_hs; w.W[1] = Wr_hs; w.W[2] = Wl_vh;
        w.W[3] = Wr_vh; w.W[4] = Wl_jv; w.W[5] = Wr_jv;
        int tot = ptot + 6 * 8192;
        init_wt_kernel<<<(tot + 255) / 256, 256, 0, stream>>>(head_all, ptot, w, Wt);
    }

    // L1: mega = 6 MFMA GEMMs + link3
    {
        GemmJobs j;
        const float* Xs[6] = {x_host, x_switch, x_vm, x_host, x_job, x_vm};
        const float* bs[6] = {bl_hs, br_hs, bl_vh, br_vh, bl_jv, br_jv};
        __half* Ys[6] = {xl_hs, xr_hs, xl_vh, xr_vh, xl_jv, xr_jv};
        int Ms[6] = {NH, NSW, NV, NH, NJ, NV};
        int base = 0;
        for (int k = 0; k < 6; k++) {
            j.X[k] = Xs[k]; j.b[k] = bs[k]; j.Y[k] = Ys[k]; j.M[k] = Ms[k];
            j.base[k] = base;
            base += (Ms[k] + 63) / 64;
        }
        j.base[6] = base;
        int L = 3072;
        int T = base + L;
        int s = T / L; if (s < 1) s = 1;
        mega_gemm_link_kernel<<<T, 256, 0, stream>>>(
            j, Wt, s, L, e_hs_dst, e_hs_src, e_vh_dst, e_vh_src,
            e_jv_dst, e_jv_src, head_all, nxt_all, EHS, EVH, EJV, pb1, pb2);
    }

    // L2: merged agg (3 relations, 32 dst per block)
    {
        AggJobs aj;
        aj.r[0] = {xl_hs, xr_hs, att_hs, head_all + 0, nxt_all + 0,
                   a_hs, dn_all + 0,
                   bias_hs, W_switch, b_switch, s_sw, NSW};
        aj.r[1] = {xl_vh, xr_vh, att_vh, head_all + pb1, nxt_all + EHS,
                   a_vh, dn_all + (size_t)pb1 * 4,
                   bias_vh, W_host, b_host, s_host, NH};
        aj.r[2] = {xl_jv, xr_jv, att_jv, head_all + pb2, nxt_all + (EHS + EVH),
                   a_jv, dn_all + (size_t)pb2 * 4,
                   bias_jv, W_vm, b_vm, s_vm, NV};
        aj.base[0] = 0;
        aj.base[1] = (NSW + 31) / 32;
        aj.base[2] = aj.base[1] + (NH + 31) / 32;
        aj.base[3] = aj.base[2] + (NV + 31) / 32;
        agg3_kernel<<<aj.base[3], 256, 0, stream>>>(aj);
    }

    // L3: alpha (all relations) + job scores
    {
        int ab = (Etot * 4 + 255) / 256;
        int jb = (NJ + 255) / 256;
        alpha_job_kernel<<<ab + jb, 256, 0, stream>>>(
            a_hs, e_hs_dst, e_vh_dst, e_jv_dst, dn_all,
            EHS, EVH, EJV, pb1, pb2, ab, b_job, s_job, NJ);
    }
}

// Round 3
// 367.472 us; speedup vs baseline: 1.1171x; 1.0674x over previous
//
#include <hip/hip_runtime.h>
#include <hip/hip_fp16.h>

// ---------------------------------------------------------------------------
// HeteroIncidentGATv2: 3 bipartite GATv2 relations (H=4, C=32, HC=128)
//   hs: host->switch (200K), vh: vm->host (400K), jv: job->vm (800K)
//
// R15 changes vs R14 (392us; mega 118us pinned across R12/R13/R14 variants,
// VGPR=44 proved the compiler sank the hoisted W loads back into the loop;
// occupancy 60->46% with zero dur change proved waves aren't binding):
//   - mega GEMM side rewritten as PERSISTENT blocks: ~1664 blocks, each owns
//     ONE job and stride-loops its 64-row tiles. W fragments (16 x half8) +
//     bias hoisted as loop-INVARIANTS of a multi-trip loop -- the compiler
//     cannot sink loads into a loop, so the hoist finally sticks (VGPR ~120).
//   - X tile t+1 prefetched at top of iteration t: every wave permanently
//     has 4KB of HBM loads in flight behind counted vmcnt.
//   - link3 = first 384 blocks, grid-stride (same atomicExch chain build).
//   - agg3 / init / alpha unchanged from R12.
// ---------------------------------------------------------------------------

#define SLOPE_ATT 0.2f
#define SLOPE_OUT 0.01f

typedef _Float16 half8_t __attribute__((ext_vector_type(8)));
typedef _Float16 v2h_t __attribute__((ext_vector_type(2)));
typedef float float4_t __attribute__((ext_vector_type(4)));

__device__ __forceinline__ float dot8(half8_t a, half8_t b, float acc) {
    v2h_t a0 = __builtin_shufflevector(a, a, 0, 1);
    v2h_t a1 = __builtin_shufflevector(a, a, 2, 3);
    v2h_t a2 = __builtin_shufflevector(a, a, 4, 5);
    v2h_t a3 = __builtin_shufflevector(a, a, 6, 7);
    v2h_t b0 = __builtin_shufflevector(b, b, 0, 1);
    v2h_t b1 = __builtin_shufflevector(b, b, 2, 3);
    v2h_t b2 = __builtin_shufflevector(b, b, 4, 5);
    v2h_t b3 = __builtin_shufflevector(b, b, 6, 7);
    acc = __builtin_amdgcn_fdot2(a0, b0, acc, false);
    acc = __builtin_amdgcn_fdot2(a1, b1, acc, false);
    acc = __builtin_amdgcn_fdot2(a2, b2, acc, false);
    acc = __builtin_amdgcn_fdot2(a3, b3, acc, false);
    return acc;
}

// ---------------------------------------------------------------------------
// L0: head = -1  +  convert 6 W matrices to fp16 transposed [n][k] layout.
// ---------------------------------------------------------------------------
struct WSrc { const float* W[6]; };

__global__ __launch_bounds__(256) void init_wt_kernel(
    int* __restrict__ head, int ptot, WSrc wsrc, __half* __restrict__ Wt) {
    int i = blockIdx.x * 256 + threadIdx.x;
    if (i < ptot) {
        head[i] = -1;
    } else {
        int r = i - ptot;
        if (r < 6 * 8192) {
            int j = r >> 13;           // which W
            int rr = r & 8191;         // n*64 + k
            int n = rr >> 6, k = rr & 63;
            Wt[r] = (__half)wsrc.W[j][k * 128 + n];
        }
    }
}

// ---------------------------------------------------------------------------
// Linked-list build: old = atomicExch(&head[slot], le); nxt[ge] = {old, src}
// ---------------------------------------------------------------------------
__device__ __forceinline__ void link_work(
    int linkId, int linkBlocks,
    const int* __restrict__ d0, const int* __restrict__ s0,
    const int* __restrict__ d1, const int* __restrict__ s1,
    const int* __restrict__ d2, const int* __restrict__ s2,
    int* __restrict__ head, int2* __restrict__ nxt,
    int E0, int E1, int E2, int pb1, int pb2) {
    int i = linkId * 256 + threadIdx.x;
    int Etot = E0 + E1 + E2;
    int stride = linkBlocks * 256;
    for (; i < Etot; i += stride) {
        int le, slot; const int* sp;
        if (i < E0)           { le = i;           slot = d0[le];       sp = s0; }
        else if (i < E0 + E1) { le = i - E0;      slot = pb1 + d1[le]; sp = s1; }
        else                  { le = i - E0 - E1; slot = pb2 + d2[le]; sp = s2; }
        int old = atomicExch(&head[slot], le);
        nxt[i] = make_int2(old, sp[le]);
    }
}

// ---------------------------------------------------------------------------
// Mega: persistent GEMM workers (job-partitioned, tile stride loop) + link3.
// Frag layouts (gfx950 16x16x32): A[m=lane&15][k=quad*8+j],
// B[n=lane&15][k=quad*8+j], C/D col=lane&15, row=quad*4+reg.
// W frags + bias are loop-invariant registers; X prefetched 1 tile ahead.
// No barrier: sY[wv] slice is wave-private, DS pipe is in-order per wave.
// ---------------------------------------------------------------------------
struct GemmJobs {
    const float* X[6]; const float* b[6]; __half* Y[6];
    int M[6]; int pbase[7];     // pbase: persistent-block partition
};

__global__ __launch_bounds__(256) void mega_gemm_link_kernel(
    GemmJobs j, const __half* __restrict__ Wt, int LB,
    const int* __restrict__ d0, const int* __restrict__ s0,
    const int* __restrict__ d1, const int* __restrict__ s1,
    const int* __restrict__ d2, const int* __restrict__ s2,
    int* __restrict__ head, int2* __restrict__ nxt,
    int E0, int E1, int E2, int pb1, int pb2) {
    __shared__ __half sY[4][16][136];
    int b = blockIdx.x;
    if (b < LB) {
        link_work(b, LB, d0, s0, d1, s1, d2, s2, head, nxt, E0, E1, E2, pb1, pb2);
        return;
    }
    int bb = b - LB;
    int k = 0;
    while (bb >= j.pbase[k + 1]) k++;
    const int p = bb - j.pbase[k];
    const int gb = j.pbase[k + 1] - j.pbase[k];
    const int M = j.M[k];
    const int nb = (M + 63) >> 6;
    if (p >= nb) return;
    const float* __restrict__ X = j.X[k];
    __half* __restrict__ Y = j.Y[k];
    const float* __restrict__ bb_ = j.b[k];
    const __half* __restrict__ W = Wt + (size_t)k * 8192;

    const int lane = threadIdx.x & 63;
    const int wv = threadIdx.x >> 6;
    const int mr = lane & 15;
    const int quad = lane >> 4;

    // loop-invariant: all 16 W fragments + 8 bias values live in registers
    half8_t wb0[8], wb1[8];
    float bv[8];
#pragma unroll
    for (int t = 0; t < 8; t++) {
        const __half* wp = W + ((size_t)(t * 16 + mr)) * 64 + quad * 8;
        wb0[t] = *(const half8_t*)wp;
        wb1[t] = *(const half8_t*)(wp + 32);
        bv[t] = bb_[t * 16 + mr];
    }

    // prefetch first X tile
    float4 xc0 = {}, xc1 = {}, xc2 = {}, xc3 = {};
    {
        int gr = p * 64 + wv * 16 + mr;
        if (gr < M) {
            const float4* xp = (const float4*)(X + (size_t)gr * 64 + quad * 8);
            xc0 = xp[0]; xc1 = xp[1];
            const float4* xq = (const float4*)(X + (size_t)gr * 64 + 32 + quad * 8);
            xc2 = xq[0]; xc3 = xq[1];
        }
    }

    for (int t = p; t < nb; t += gb) {
        // issue next tile's X loads first (in flight across this iteration)
        int tn = t + gb;
        float4 xn0 = {}, xn1 = {}, xn2 = {}, xn3 = {};
        if (tn < nb) {
            int gr = tn * 64 + wv * 16 + mr;
            if (gr < M) {
                const float4* xp = (const float4*)(X + (size_t)gr * 64 + quad * 8);
                xn0 = xp[0]; xn1 = xp[1];
                const float4* xq = (const float4*)(X + (size_t)gr * 64 + 32 + quad * 8);
                xn2 = xq[0]; xn3 = xq[1];
            }
        }

        half8_t a0, a1;
        a0[0] = (_Float16)xc0.x; a0[1] = (_Float16)xc0.y;
        a0[2] = (_Float16)xc0.z; a0[3] = (_Float16)xc0.w;
        a0[4] = (_Float16)xc1.x; a0[5] = (_Float16)xc1.y;
        a0[6] = (_Float16)xc1.z; a0[7] = (_Float16)xc1.w;
        a1[0] = (_Float16)xc2.x; a1[1] = (_Float16)xc2.y;
        a1[2] = (_Float16)xc2.z; a1[3] = (_Float16)xc2.w;
        a1[4] = (_Float16)xc3.x; a1[5] = (_Float16)xc3.y;
        a1[6] = (_Float16)xc3.z; a1[7] = (_Float16)xc3.w;

        const int m0 = t * 64 + wv * 16;
#pragma unroll
        for (int tt = 0; tt < 8; tt++) {
            float4_t c = {0.f, 0.f, 0.f, 0.f};
            c = __builtin_amdgcn_mfma_f32_16x16x32_f16(a0, wb0[tt], c, 0, 0, 0);
            c = __builtin_amdgcn_mfma_f32_16x16x32_f16(a1, wb1[tt], c, 0, 0, 0);
            int ocol = tt * 16 + mr;
            int lrow = quad * 4;
#pragma unroll
            for (int r = 0; r < 4; r++)
                sY[wv][lrow + r][ocol] = (__half)(c[r] + bv[tt]);
        }

        // wave-private LDS transpose -> coalesced 16B stores (no barrier)
        const int c8 = mr * 8;
#pragma unroll
        for (int i = 0; i < 4; i++) {
            int row = i * 4 + quad;
            int gr2 = m0 + row;
            if (gr2 < M) {
                half8_t v = *(const half8_t*)&sY[wv][row][c8];
                *(half8_t*)&Y[(size_t)gr2 * 128 + c8] = v;
            }
        }

        xc0 = xn0; xc1 = xn1; xc2 = xn2; xc3 = xn3;
    }
}

// ---------------------------------------------------------------------------
// Fused GATv2 aggregate: 8 dst per 64-lane wave (8 lanes/dst, 16 ch/lane).
// Per group: walk the dst's chain; per edge: in-lane fdot2 over 16 ch +
// one shfl_xor(1) -> head logit; w = exp(p); acc += w*x (fp32, 16 ch).
// ex/dn writes 16B-contiguous per group. Fused readout epilogue.
// ---------------------------------------------------------------------------
struct AggJob {
    const __half* xl; const __half* xr; const float* att;
    const int* head; const int2* nxt;
    float* ex; float* dn;
    const float* bias; const float* Wn; const float* bn; float* scores;
    int Nd;
};
struct AggJobs { AggJob r[3]; int base[4]; };   // base in BLOCKS (32 dst/block)

__global__ __launch_bounds__(256) void agg3_kernel(AggJobs aj) {
    int b = blockIdx.x;
    int k = 0;
    while (b >= aj.base[k + 1]) k++;
    AggJob J = aj.r[k];

    const int l = threadIdx.x & 63;
    const int wv = threadIdx.x >> 6;
    const int li = l & 7;                 // lane in group
    const int g = l >> 3;                 // group 0..7
    const int dbase = ((b - aj.base[k]) * 4 + wv) * 8;
    const int d = dbase + g;
    if (dbase >= J.Nd) return;
    const bool dok = d < J.Nd;
    const int h = li >> 1;                // my head (pair of lanes per head)

    // my 16 channels: 2 x half8
    half8_t xr0 = {}, xr1 = {};
    if (dok) {
        const half8_t* xrp = (const half8_t*)(J.xr + (size_t)d * 128) + li * 2;
        xr0 = xrp[0]; xr1 = xrp[1];
    }
    half8_t at0, at1;
    {
        const float* ap = J.att + li * 16;
#pragma unroll
        for (int i = 0; i < 8; i++) {
            at0[i] = (_Float16)ap[i];
            at1[i] = (_Float16)ap[8 + i];
        }
    }
    const half8_t sl8 = {(_Float16)SLOPE_ATT, (_Float16)SLOPE_ATT,
                         (_Float16)SLOPE_ATT, (_Float16)SLOPE_ATT,
                         (_Float16)SLOPE_ATT, (_Float16)SLOPE_ATT,
                         (_Float16)SLOPE_ATT, (_Float16)SLOPE_ATT};

    float acc[16] = {};
    float ssum = 0.f;

    int e = dok ? J.head[d] : -1;
    const bool any = (e >= 0);

    while (__any(e >= 0)) {
        bool act = (e >= 0);
        int2 ns = act ? J.nxt[e] : make_int2(-1, 0);
        half8_t x0 = {}, x1 = {};
        if (act) {
            const half8_t* xp = (const half8_t*)(J.xl + (size_t)ns.y * 128) + li * 2;
            x0 = xp[0]; x1 = xp[1];
        }
        if (act) {
            half8_t v0 = x0 + xr0;
            half8_t v1 = x1 + xr1;
            half8_t lk0 = __builtin_elementwise_max(v0, v0 * sl8);
            half8_t lk1 = __builtin_elementwise_max(v1, v1 * sl8);
            float p = dot8(lk1, at1, dot8(lk0, at0, 0.f));
            p += __shfl_xor(p, 1);            // pair shares one head
            float w = __expf(p);
            if ((li & 1) == 0) J.ex[(size_t)e * 4 + h] = w;
            ssum += w;
#pragma unroll
            for (int i = 0; i < 8; i++) {
                acc[i]     += w * (float)x0[i];
                acc[8 + i] += w * (float)x1[i];
            }
        }
        e = act ? ns.x : -1;
    }

    if (dok && (li & 1) == 0) J.dn[(size_t)d * 4 + h] = ssum;

    // readout: sigmoid(lrelu(acc/ssum + bias, .01) . Wn + bn)
    float rr = any ? 1.f / ssum : 0.f;
    float pr = 0.f;
    if (dok) {
        const float* bp = J.bias + li * 16;
        const float* wp = J.Wn + li * 16;
#pragma unroll
        for (int i = 0; i < 16; i++) {
            float o = acc[i] * rr + bp[i];
            o = o > 0.f ? o : SLOPE_OUT * o;
            pr += o * wp[i];
        }
    }
    pr += __shfl_xor(pr, 1);
    pr += __shfl_xor(pr, 2);
    pr += __shfl_xor(pr, 4);
    if (dok && li == 0)
        J.scores[d] = 1.f / (1.f + __expf(-(pr + J.bn[0])));
}

// ---------------------------------------------------------------------------
// Merged: alpha (= ex/dn) for all relations + job scores.
// ---------------------------------------------------------------------------
__global__ __launch_bounds__(256) void alpha_job_kernel(
    float* __restrict__ ex,
    const int* __restrict__ d0, const int* __restrict__ d1,
    const int* __restrict__ d2,
    const float* __restrict__ dn,
    int E0, int E1, int E2, int pb1, int pb2, int ab,
    const float* __restrict__ bjob, float* __restrict__ sjob, int NJ) {
    int b = blockIdx.x;
    if (b < ab) {
        int i = b * 256 + threadIdx.x;
        int tot = (E0 + E1 + E2) * 4;
        if (i >= tot) return;
        int e = i >> 2, h = i & 3;
        int d;
        if (e < E0)           d = d0[e];
        else if (e < E0 + E1) d = pb1 + d1[e - E0];
        else                  d = pb2 + d2[e - E0 - E1];
        ex[i] = ex[i] / dn[(size_t)d * 4 + h];
    } else {
        int i = (b - ab) * 256 + threadIdx.x;
        if (i < NJ) sjob[i] = 1.f / (1.f + __expf(-bjob[0]));
    }
}

// ---------------------------------------------------------------------------

extern "C" void kernel_launch(void* const* d_in, const int* in_sizes, int n_in,
                              void* d_out, int out_size, void* d_ws, size_t ws_size,
                              hipStream_t stream) {
    const float* x_host   = (const float*)d_in[0];
    const float* x_vm     = (const float*)d_in[1];
    const float* x_job    = (const float*)d_in[2];
    const float* x_switch = (const float*)d_in[3];
    const int* e_hs_src = (const int*)d_in[4];
    const int* e_hs_dst = (const int*)d_in[5];
    const int* e_vh_src = (const int*)d_in[6];
    const int* e_vh_dst = (const int*)d_in[7];
    const int* e_jv_src = (const int*)d_in[8];
    const int* e_jv_dst = (const int*)d_in[9];
    const float* Wl_hs = (const float*)d_in[10];
    const float* bl_hs = (const float*)d_in[11];
    const float* Wr_hs = (const float*)d_in[12];
    const float* br_hs = (const float*)d_in[13];
    const float* att_hs = (const float*)d_in[14];
    const float* bias_hs = (const float*)d_in[15];
    const float* Wl_vh = (const float*)d_in[16];
    const float* bl_vh = (const float*)d_in[17];
    const float* Wr_vh = (const float*)d_in[18];
    const float* br_vh = (const float*)d_in[19];
    const float* att_vh = (const float*)d_in[20];
    const float* bias_vh = (const float*)d_in[21];
    const float* Wl_jv = (const float*)d_in[22];
    const float* bl_jv = (const float*)d_in[23];
    const float* Wr_jv = (const float*)d_in[24];
    const float* br_jv = (const float*)d_in[25];
    const float* att_jv = (const float*)d_in[26];
    const float* bias_jv = (const float*)d_in[27];
    const float* W_host   = (const float*)d_in[28];
    const float* b_host   = (const float*)d_in[29];
    const float* W_vm     = (const float*)d_in[30];
    const float* b_vm     = (const float*)d_in[31];
    const float* W_job    = (const float*)d_in[32];
    const float* b_job    = (const float*)d_in[33];
    const float* W_switch = (const float*)d_in[34];
    const float* b_switch = (const float*)d_in[35];

    const int NH  = in_sizes[0] / 64;
    const int NV  = in_sizes[1] / 64;
    const int NJ  = in_sizes[2] / 64;
    const int NSW = in_sizes[3] / 64;
    const int EHS = in_sizes[4];
    const int EVH = in_sizes[6];
    const int EJV = in_sizes[8];
    const int Etot = EHS + EVH + EJV;

    float* out = (float*)d_out;
    float* s_host = out;
    float* s_vm = out + NH;
    float* s_job = out + NH + NV;
    float* s_sw = out + NH + NV + NJ;
    float* a_hs = out + NH + NV + NJ + NSW;
    float* a_vh = a_hs + (size_t)EHS * 4;
    float* a_jv = a_vh + (size_t)EVH * 4;

    const int pb1 = ((NSW + 255) / 256) * 256;
    const int pb2 = pb1 + ((NH + 255) / 256) * 256;
    const int ptot = pb2 + ((NV + 255) / 256) * 256;

    // -------- ws layout (~137 MB total) --------
    float* ws = (float*)d_ws;
    int2* nxt_all = (int2*)ws;                              // Etot int2
    int* head_all = (int*)(nxt_all + Etot);                 // ptot
    float* dn_all = (float*)(head_all + ptot);              // ptot*4
    __half* Wt    = (__half*)(dn_all + (size_t)ptot * 4);   // 6*8192 fp16
    __half* mats  = Wt + 6 * 8192;
    __half* xl_hs = mats;                                   // NH*128
    __half* xr_hs = xl_hs + (size_t)NH * 128;               // NSW*128
    __half* xl_vh = xr_hs + (size_t)NSW * 128;              // NV*128
    __half* xr_vh = xl_vh + (size_t)NV * 128;               // NH*128
    __half* xl_jv = xr_vh + (size_t)NH * 128;               // NJ*128
    __half* xr_jv = xl_jv + (size_t)NJ * 128;               // NV*128

    // L0: head = -1 + Wt conversion
    {
        WSrc w;
        w.W[0] = Wl_hs; w.W[1] = Wr_hs; w.W[2] = Wl_vh;
        w.W[3] = Wr_vh; w.W[4] = Wl_jv; w.W[5] = Wr_jv;
        int tot = ptot + 6 * 8192;
        init_wt_kernel<<<(tot + 255) / 256, 256, 0, stream>>>(head_all, ptot, w, Wt);
    }

    // L1: mega = persistent GEMM workers + link3
    {
        GemmJobs j;
        const float* Xs[6] = {x_host, x_switch, x_vm, x_host, x_job, x_vm};
        const float* bs[6] = {bl_hs, br_hs, bl_vh, br_vh, bl_jv, br_jv};
        __half* Ys[6] = {xl_hs, xr_hs, xl_vh, xr_vh, xl_jv, xr_jv};
        int Ms[6] = {NH, NSW, NV, NH, NJ, NV};
        int nbk[6]; long long total_nb = 0;
        for (int k = 0; k < 6; k++) { nbk[k] = (Ms[k] + 63) / 64; total_nb += nbk[k]; }
        const int GBTOT = 1664;     // persistent GEMM blocks (~6.5/CU)
        const int LB = 384;         // link blocks
        int pb = 0;
        for (int k = 0; k < 6; k++) {
            j.X[k] = Xs[k]; j.b[k] = bs[k]; j.Y[k] = Ys[k]; j.M[k] = Ms[k];
            j.pbase[k] = pb;
            int gb = (int)(((long long)GBTOT * nbk[k]) / total_nb);
            if (gb < 1) gb = 1;
            pb += gb;
        }
        j.pbase[6] = pb;
        mega_gemm_link_kernel<<<LB + pb, 256, 0, stream>>>(
            j, Wt, LB, e_hs_dst, e_hs_src, e_vh_dst, e_vh_src,
            e_jv_dst, e_jv_src, head_all, nxt_all, EHS, EVH, EJV, pb1, pb2);
    }

    // L2: merged agg (3 relations, 32 dst per block)
    {
        AggJobs aj;
        aj.r[0] = {xl_hs, xr_hs, att_hs, head_all + 0, nxt_all + 0,
                   a_hs, dn_all + 0,
                   bias_hs, W_switch, b_switch, s_sw, NSW};
        aj.r[1] = {xl_vh, xr_vh, att_vh, head_all + pb1, nxt_all + EHS,
                   a_vh, dn_all + (size_t)pb1 * 4,
                   bias_vh, W_host, b_host, s_host, NH};
        aj.r[2] = {xl_jv, xr_jv, att_jv, head_all + pb2, nxt_all + (EHS + EVH),
                   a_jv, dn_all + (size_t)pb2 * 4,
                   bias_jv, W_vm, b_vm, s_vm, NV};
        aj.base[0] = 0;
        aj.base[1] = (NSW + 31) / 32;
        aj.base[2] = aj.base[1] + (NH + 31) / 32;
        aj.base[3] = aj.base[2] + (NV + 31) / 32;
        agg3_kernel<<<aj.base[3], 256, 0, stream>>>(aj);
    }

    // L3: alpha (all relations) + job scores
    {
        int ab = (Etot * 4 + 255) / 256;
        int jb = (NJ + 255) / 256;
        alpha_job_kernel<<<ab + jb, 256, 0, stream>>>(
            a_hs, e_hs_dst, e_vh_dst, e_jv_dst, dn_all,
            EHS, EVH, EJV, pb1, pb2, ab, b_job, s_job, NJ);
    }
}